// Round 1
// 198.085 us; speedup vs baseline: 1.0175x; 1.0175x over previous
//
#include <hip/hip_runtime.h>
#include <math.h>

namespace {
constexpr int S = 7;
constexpr int B = 2;
constexpr int C = 20;
constexpr int PF = B * 5 + C;   // 30 floats per cell (predictions)
constexpr int TF = 5 + C;       // 25 floats per cell (targets)
constexpr float EPS = 1e-6f;
constexpr float LAMBDA_COORD = 5.0f;
constexpr float LAMBDA_NOOBJ = 0.5f;
constexpr int BLK = 256;
constexpr int CH = 256;                  // cells per block (== BLK)
constexpr int PRED_FLOATS = CH * PF;     // 7680 floats = 30720 B
constexpr int TGT_FLOATS  = CH * TF;     // 6400 floats = 25600 B
}

#define GLOBAL_AS __attribute__((address_space(1)))
#define LDS_AS    __attribute__((address_space(3)))

// Stage each block's 256 cells (pred: 30 floats, tgt: 25 floats) into LDS via
// coalesced async global_load_lds (16B/lane), then compute from LDS. This
// converts the 120B/100B-stride scattered AoS loads (transaction/latency
// bound, 17% HBM) into a pure dwordx4 HBM stream.
__global__ __launch_bounds__(BLK) void k_main(const float* __restrict__ pred,
                                              const float* __restrict__ tgt,
                                              float* __restrict__ part,
                                              int n_cells) {
    __shared__ float lp[PRED_FLOATS];
    __shared__ float lt[TGT_FLOATS];

    const int tid = threadIdx.x;
    const int block0 = blockIdx.x * CH;
    const int remc = n_cells - block0;
    const int cells = remc < CH ? remc : CH;

    const size_t pbase = (size_t)block0 * PF;
    const size_t tbase = (size_t)block0 * TF;

    if (cells == CH) {
        // Fast path: full chunk, async direct-to-LDS, 16B per lane per call.
        // LDS dest is linear in the exact lane order (wave-uniform base +
        // lane*16) -- required by global_load_lds.
        #pragma unroll
        for (int o = 0; o < PRED_FLOATS; o += BLK * 4) {
            const int idx = o + tid * 4;
            if (idx < PRED_FLOATS) {
                __builtin_amdgcn_global_load_lds(
                    (const GLOBAL_AS void*)(pred + pbase + idx),
                    (LDS_AS void*)(lp + idx), 16, 0, 0);
            }
        }
        #pragma unroll
        for (int o = 0; o < TGT_FLOATS; o += BLK * 4) {
            const int idx = o + tid * 4;
            if (idx < TGT_FLOATS) {
                __builtin_amdgcn_global_load_lds(
                    (const GLOBAL_AS void*)(tgt + tbase + idx),
                    (LDS_AS void*)(lt + idx), 16, 0, 0);
            }
        }
        asm volatile("s_waitcnt vmcnt(0)" ::: "memory");
    } else {
        // Cold path: partial tail chunk (unused for the bench shape).
        for (int o = tid; o < cells * PF; o += BLK) lp[o] = pred[pbase + o];
        for (int o = tid; o < cells * TF; o += BLK) lt[o] = tgt[tbase + o];
    }
    __syncthreads();

    float v0 = 0.f, v1 = 0.f, v2 = 0.f, v3 = 0.f;
    if (tid < cells) {
        const int cell = block0 + tid;
        const float* p = lp + tid * PF;   // LDS, stride 30: 2-way bank alias (free)
        const float* t = lt + tid * TF;   // LDS, stride 25: conflict-free

        const float c0 = p[4], c1 = p[9];
        const float t4 = t[4];

        v2 = c0 * c0 + c1 * c1;                       // noobj base term

        if (t4 > 0.f) {                               // ~6% of lanes
            const int j = cell % S;
            const int i = (cell / S) % S;
            const float invS = 1.0f / (float)S;

            const float2 p01 = *(const float2*)(p + 0);   // (x0, y0)
            const float2 p23 = *(const float2*)(p + 2);   // (w0, h0)
            const float2 p67 = *(const float2*)(p + 6);   // (y1, w1)
            const float gx = t[0], gy = t[1], gw = t[2], gh = t[3];

            // ground-truth abs box
            const float gcx = ((float)j + gx) * invS;
            const float gcy = ((float)i + gy) * invS;
            const float gx1 = gcx - gw * 0.5f, gy1 = gcy - gh * 0.5f;
            const float gx2 = gcx + gw * 0.5f, gy2 = gcy + gh * 0.5f;
            const float garea = (gx2 - gx1) * (gy2 - gy1);

            const float bx[B]  = {p01.x, p[5]};
            const float by[B]  = {p01.y, p67.x};
            const float bw_[B] = {p23.x, p67.y};
            const float bh[B]  = {p23.y, p[8]};
            const float cf[B]  = {c0, c1};
            float iou[B];
            #pragma unroll
            for (int b = 0; b < B; ++b) {
                const float cx = ((float)j + bx[b]) * invS;
                const float cy = ((float)i + by[b]) * invS;
                const float x1 = cx - bw_[b] * 0.5f, y1 = cy - bh[b] * 0.5f;
                const float x2 = cx + bw_[b] * 0.5f, y2 = cy + bh[b] * 0.5f;
                const float ix1 = fmaxf(x1, gx1), iy1 = fmaxf(y1, gy1);
                const float ix2 = fminf(x2, gx2), iy2 = fminf(y2, gy2);
                const float inter = fmaxf(ix2 - ix1, 0.f) * fmaxf(iy2 - iy1, 0.f);
                const float parea = (x2 - x1) * (y2 - y1);
                iou[b] = inter / (parea + garea - inter + EPS);
            }
            const int best = (iou[1] > iou[0]) ? 1 : 0;   // first max wins
            const float rconf = cf[best], riou = iou[best];

            const float dx = bx[best] - gx, dy = by[best] - gy;
            const float swd = sqrtf(bw_[best] + EPS) - sqrtf(gw + EPS);
            const float shd = sqrtf(bh[best] + EPS) - sqrtf(gh + EPS);
            v0 = dx*dx + dy*dy + swd*swd + shd*shd;       // coord
            const float dc = rconf - riou;
            v1 = dc * dc;                                  // conf_obj
            v2 -= rconf * rconf;                           // responsible box excluded

            // class: lse*sum(g) - dot(g,l). Logits in [0,1) -> no max pass needed.
            float se = 0.f, dot = 0.f, sg = 0.f;
            #pragma unroll
            for (int c = 0; c < C; c += 2) {
                const float2 lc = *(const float2*)(p + 10 + c);
                const float g0 = t[5 + c], g1 = t[6 + c];
                se  += __expf(lc.x) + __expf(lc.y);
                dot += g0 * lc.x + g1 * lc.y;
                sg  += g0 + g1;
            }
            v3 = __logf(se) * sg - dot;                    // class
        }
    }

    // ---- reduce: wave64 butterfly -> LDS -> per-block partial slot ----
    float v[4] = {v0, v1, v2, v3};
    #pragma unroll
    for (int off = 32; off >= 1; off >>= 1) {
        v[0] += __shfl_down(v[0], off, 64);
        v[1] += __shfl_down(v[1], off, 64);
        v[2] += __shfl_down(v[2], off, 64);
        v[3] += __shfl_down(v[3], off, 64);
    }
    __shared__ float red[16];   // 4 waves x 4 sums
    const int lane = tid & 63;
    const int wave = tid >> 6;
    if (lane == 0) {
        red[wave * 4 + 0] = v[0];
        red[wave * 4 + 1] = v[1];
        red[wave * 4 + 2] = v[2];
        red[wave * 4 + 3] = v[3];
    }
    __syncthreads();
    if (tid < 4)
        part[blockIdx.x * 4 + tid] =
            red[tid] + red[4 + tid] + red[8 + tid] + red[12 + tid];
}

// Single block: reduce nblk x 4 partials, write 5 outputs.
__global__ __launch_bounds__(BLK) void k_fin(const float* __restrict__ part,
                                             float* __restrict__ out,
                                             int nblk, float n) {
    const int tid = threadIdx.x;
    float a0 = 0.f, a1 = 0.f, a2 = 0.f, a3 = 0.f;
    for (int r = tid; r < nblk; r += BLK) {
        const float4 q = *(const float4*)(part + r * 4);
        a0 += q.x; a1 += q.y; a2 += q.z; a3 += q.w;
    }
    float v[4] = {a0, a1, a2, a3};
    #pragma unroll
    for (int off = 32; off >= 1; off >>= 1) {
        v[0] += __shfl_down(v[0], off, 64);
        v[1] += __shfl_down(v[1], off, 64);
        v[2] += __shfl_down(v[2], off, 64);
        v[3] += __shfl_down(v[3], off, 64);
    }
    __shared__ float red[16];
    const int lane = tid & 63;
    const int wave = tid >> 6;
    if (lane == 0) {
        red[wave * 4 + 0] = v[0];
        red[wave * 4 + 1] = v[1];
        red[wave * 4 + 2] = v[2];
        red[wave * 4 + 3] = v[3];
    }
    __syncthreads();
    if (tid == 0) {
        const float coord  = red[0] + red[4] + red[8] + red[12];
        const float cobj   = red[1] + red[5] + red[9] + red[13];
        const float cnoobj = red[2] + red[6] + red[10] + red[14];
        const float ccls   = red[3] + red[7] + red[11] + red[15];
        const float inv = 1.0f / n;
        out[0] = coord * inv;
        out[1] = cobj * inv;
        out[2] = cnoobj * inv;
        out[3] = ccls * inv;
        out[4] = (LAMBDA_COORD * coord + cobj + LAMBDA_NOOBJ * cnoobj + ccls) * inv;
    }
}

extern "C" void kernel_launch(void* const* d_in, const int* in_sizes, int n_in,
                              void* d_out, int out_size, void* d_ws, size_t ws_size,
                              hipStream_t stream) {
    const float* pred = (const float*)d_in[0];
    const float* tgt  = (const float*)d_in[1];
    float* out  = (float*)d_out;
    float* part = (float*)d_ws;

    const int n_cells = in_sizes[0] / PF;          // 802816
    const float bs = (float)(n_cells / (S * S));   // 16384
    const int nblk = (n_cells + CH - 1) / CH;      // 3136

    k_main<<<nblk, BLK, 0, stream>>>(pred, tgt, part, n_cells);
    k_fin<<<1, BLK, 0, stream>>>(part, out, nblk, bs);
}